// Round 5
// baseline (282.798 us; speedup 1.0000x reference)
//
#include <hip/hip_runtime.h>

// PhotometricLoss: fused warp + SSIM(3x3 avgpool, zero-pad) + L1 + masked mean.
// B=8, C=3, H=720, W=1280 fp32.
//
// R5: all global streams are float4 (16B/lane); the bilinear right-gather goes
// through a per-wave LDS window (256px strip + 32px halo each side), stored
// transposed by px%4 (stride 81) so gather addresses are lane-stride-1 ->
// near-conflict-free ds_read_b32. Channels = 3 sequential passes (SSIM/L1 are
// channel-additive) to keep the register ring tiny (raw x,y 3-row ring).
// Pipeline: load right r+2 / stage right r+1 / gather r; disp-left depth-1.
// Strip-edge pooling neighbors: lanes 0/63 each compute one boundary pixel.

#define P_ALPHA 0.85f
#define P_C1 1e-4f
#define P_C2 9e-4f

constexpr int W_ = 1280, H_ = 720;
constexpr int HW_ = W_ * H_;
constexpr int RPW = 6;        // rows per wave; 720 = 30 * (4 waves * 6 rows)
constexpr int NW  = 4;        // waves per block
constexpr int SST = 81;       // LDS sub-array stride (80 + 1 pad)

__global__ __launch_bounds__(256)
void photo_loss_kernel(const float* __restrict__ disp,
                       const float* __restrict__ left,
                       const float* __restrict__ right,
                       float* __restrict__ acc)   // acc[0]=sum(photo*valid), acc[1]=sum(valid)
{
    __shared__ float lds[NW][2][4 * SST];   // per-wave double-buffered right window
    __shared__ float redpv[NW], redv[NW];

    const int tid  = threadIdx.x;
    const int lane = tid & 63;
    const int wv   = tid >> 6;
    const int b    = blockIdx.z;
    const int strip = blockIdx.x;
    const int base  = strip * 256;          // first px of strip
    const int wbase = base - 32;            // LDS window start (px)
    const int r0    = (blockIdx.y * NW + wv) * RPW;

    const float* __restrict__ dispb = disp + (size_t)b * HW_;
    const float4* __restrict__ D4 = (const float4*)dispb;

    // static per-lane indices (row-relative float4 indices)
    const int lq  = (base >> 2) + lane;                                  // disp/left f4
    const int rqm = (min(max(wbase + 4 * lane, 0), W_ - 4)) >> 2;        // right main f4
    const int rqh = (min(max(wbase + 256 + 4 * lane, 0), W_ - 4)) >> 2;  // right halo f4 (lanes<16)
    const int   bpx   = (lane == 63) ? base + 256 : base - 1;            // boundary px this lane tracks
    const int   bpxc  = min(max(bpx, 0), W_ - 1);
    const float bmask = (bpx >= 0 && bpx < W_) ? 1.f : 0.f;              // image-edge zero-pad
    const float px0   = (float)(base + 4 * lane);
    const float wm1   = (float)(W_ - 1);
    const bool  isL0 = (lane == 0), isL63 = (lane == 63);

    float* const bufA = &lds[wv][0][0];
    float* const bufB = &lds[wv][1][0];

    float sum_pv = 0.f, sum_v = 0.f;

    for (int c = 0; c < 3; ++c) {
        const float4* __restrict__ L4 = (const float4*)(left  + (size_t)(b * 3 + c) * HW_);
        const float4* __restrict__ R4 = (const float4*)(right + (size_t)(b * 3 + c) * HW_);
        const float*  __restrict__ Ls = left + (size_t)(b * 3 + c) * HW_;

        // 3-row raw rings (static indices after unroll)
        float xr[3][4], yr[3][4], vr[3][4], xb[3], yb[3];

        // ---- prologue: D/L row r0-1; stage right r0-1 -> bufA; right r0 -> prS ----
        const int rA = min(max(r0 - 1, 0), H_ - 1);
        float4 pd  = D4[rA * (W_ / 4) + lq];
        float4 pl  = L4[rA * (W_ / 4) + lq];
        float  pbd = dispb[rA * W_ + bpxc];
        float  pbl = Ls[rA * W_ + bpxc];
        {
            float4 t = R4[rA * (W_ / 4) + rqm];
            float4 th = make_float4(0.f, 0.f, 0.f, 0.f);
            if (lane < 16) th = R4[rA * (W_ / 4) + rqh];
            bufA[0 * SST + lane] = t.x;   // local px q=4l+k -> sub k, off l
            bufA[1 * SST + lane] = t.y;
            bufA[2 * SST + lane] = t.z;
            bufA[3 * SST + lane] = t.w;
            if (lane < 16) {
                bufA[0 * SST + 64 + lane] = th.x;
                bufA[1 * SST + 64 + lane] = th.y;
                bufA[2 * SST + 64 + lane] = th.z;
                bufA[3 * SST + 64 + lane] = th.w;
            }
        }
        float4 prS = R4[r0 * (W_ / 4) + rqm];
        float4 phS = make_float4(0.f, 0.f, 0.f, 0.f);
        if (lane < 16) phS = R4[r0 * (W_ / 4) + rqh];

        #pragma unroll
        for (int j = 0; j < RPW + 2; ++j) {
            const int   rIns = r0 - 1 + j;                    // row inserted this step
            const float m    = (rIns >= 0 && rIns < H_) ? 1.f : 0.f;

            // (a) prefetch disp/left row rIns+1
            float4 npd = make_float4(0.f,0.f,0.f,0.f), npl = npd;
            float  npbd = 0.f, npbl = 0.f;
            if (j < RPW + 1) {
                const int rn = min(max(rIns + 1, 0), H_ - 1);
                npd  = D4[rn * (W_ / 4) + lq];
                npl  = L4[rn * (W_ / 4) + lq];
                npbd = dispb[rn * W_ + bpxc];
                npbl = Ls[rn * W_ + bpxc];
            }
            // (b) prefetch right row rIns+2
            float4 nprS = make_float4(0.f,0.f,0.f,0.f), nphS = nprS;
            if (j < RPW) {
                const int rn2 = min(max(rIns + 2, 0), H_ - 1);
                nprS = R4[rn2 * (W_ / 4) + rqm];
                if (lane < 16) nphS = R4[rn2 * (W_ / 4) + rqh];
            }
            // (c) stage right row rIns+1 (prS, loaded last step) into buf[(j+1)&1]
            if (j < RPW + 1) {
                float* bw = (j & 1) ? bufA : bufB;
                bw[0 * SST + lane] = prS.x;
                bw[1 * SST + lane] = prS.y;
                bw[2 * SST + lane] = prS.z;
                bw[3 * SST + lane] = prS.w;
                if (lane < 16) {
                    bw[0 * SST + 64 + lane] = phS.x;
                    bw[1 * SST + 64 + lane] = phS.y;
                    bw[2 * SST + 64 + lane] = phS.z;
                    bw[3 * SST + 64 + lane] = phS.w;
                }
            }
            // (d) gather row rIns from buf[j&1] (staged last step)
            const float* br = (j & 1) ? bufB : bufA;
            const int s = j % 3;
            const float dq[4]  = {pd.x, pd.y, pd.z, pd.w};
            const float lqv[4] = {pl.x, pl.y, pl.z, pl.w};
            #pragma unroll
            for (int k = 0; k < 4; ++k) {
                const float xs  = (px0 + (float)k) - dq[k];
                vr[s][k] = (xs > 0.f && xs < wm1) ? 1.f : 0.f;
                const float xcl = fminf(fmaxf(xs, 0.f), wm1);
                const float xf  = floorf(xcl);
                const float fr  = xcl - xf;
                const int i0  = (int)xf;
                const int i1  = min(i0 + 1, W_ - 1);
                const int li0 = min(max(i0 - wbase, 0), 319);
                const int li1 = min(max(i1 - wbase, 0), 319);
                const float g0 = br[(li0 & 3) * SST + (li0 >> 2)];
                const float g1 = br[(li1 & 3) * SST + (li1 >> 2)];
                yr[s][k] = ((1.f - fr) * g0 + fr * g1) * m;
                xr[s][k] = lqv[k] * m;
            }
            // boundary px (lane 0: base-1, lane 63: base+256; others compute dead data)
            {
                const float xsB = (float)bpx - pbd;
                const float xcl = fminf(fmaxf(xsB, 0.f), wm1);
                const float xf  = floorf(xcl);
                const float fr  = xcl - xf;
                const int i0  = (int)xf;
                const int i1  = min(i0 + 1, W_ - 1);
                const int li0 = min(max(i0 - wbase, 0), 319);
                const int li1 = min(max(i1 - wbase, 0), 319);
                const float g0 = br[(li0 & 3) * SST + (li0 >> 2)];
                const float g1 = br[(li1 & 3) * SST + (li1 >> 2)];
                const float mb = m * bmask;
                yb[s] = ((1.f - fr) * g0 + fr * g1) * mb;
                xb[s] = pbl * mb;
            }
            // (e) emit center row rIns-1 (ring holds rIns-2..rIns)
            if (j >= 2) {
                const int sc = (j + 2) % 3;   // (j-1) mod 3
                float Vx[4], Vy[4], Vxx[4], Vyy[4], Vxy[4];
                #pragma unroll
                for (int k = 0; k < 4; ++k) {
                    const float x0 = xr[0][k], x1 = xr[1][k], x2 = xr[2][k];
                    const float y0 = yr[0][k], y1 = yr[1][k], y2 = yr[2][k];
                    Vx[k]  = x0 + x1 + x2;
                    Vy[k]  = y0 + y1 + y2;
                    Vxx[k] = x0 * x0 + x1 * x1 + x2 * x2;
                    Vyy[k] = y0 * y0 + y1 * y1 + y2 * y2;
                    Vxy[k] = x0 * y0 + x1 * y1 + x2 * y2;
                }
                const float a0 = xb[0], a1 = xb[1], a2 = xb[2];
                const float b0 = yb[0], b1 = yb[1], b2 = yb[2];
                const float VBx  = a0 + a1 + a2;
                const float VBy  = b0 + b1 + b2;
                const float VBxx = a0 * a0 + a1 * a1 + a2 * a2;
                const float VByy = b0 * b0 + b1 * b1 + b2 * b2;
                const float VBxy = a0 * b0 + a1 * b1 + a2 * b2;

                float VxL = __shfl_up(Vx[3], 1, 64);  VxL = isL0 ? VBx  : VxL;
                float VyL = __shfl_up(Vy[3], 1, 64);  VyL = isL0 ? VBy  : VyL;
                float VxxL= __shfl_up(Vxx[3],1, 64);  VxxL= isL0 ? VBxx : VxxL;
                float VyyL= __shfl_up(Vyy[3],1, 64);  VyyL= isL0 ? VByy : VyyL;
                float VxyL= __shfl_up(Vxy[3],1, 64);  VxyL= isL0 ? VBxy : VxyL;
                float VxR = __shfl_down(Vx[0], 1, 64); VxR = isL63 ? VBx  : VxR;
                float VyR = __shfl_down(Vy[0], 1, 64); VyR = isL63 ? VBy  : VyR;
                float VxxR= __shfl_down(Vxx[0],1, 64); VxxR= isL63 ? VBxx : VxxR;
                float VyyR= __shfl_down(Vyy[0],1, 64); VyyR= isL63 ? VByy : VyyR;
                float VxyR= __shfl_down(Vxy[0],1, 64); VxyR= isL63 ? VBxy : VxyR;

                float Sx[4], Sy[4], Sxx[4], Syy[4], Sxy[4];
                Sx[0]=VxL+Vx[0]+Vx[1];   Sx[1]=Vx[0]+Vx[1]+Vx[2];   Sx[2]=Vx[1]+Vx[2]+Vx[3];   Sx[3]=Vx[2]+Vx[3]+VxR;
                Sy[0]=VyL+Vy[0]+Vy[1];   Sy[1]=Vy[0]+Vy[1]+Vy[2];   Sy[2]=Vy[1]+Vy[2]+Vy[3];   Sy[3]=Vy[2]+Vy[3]+VyR;
                Sxx[0]=VxxL+Vxx[0]+Vxx[1]; Sxx[1]=Vxx[0]+Vxx[1]+Vxx[2]; Sxx[2]=Vxx[1]+Vxx[2]+Vxx[3]; Sxx[3]=Vxx[2]+Vxx[3]+VxxR;
                Syy[0]=VyyL+Vyy[0]+Vyy[1]; Syy[1]=Vyy[0]+Vyy[1]+Vyy[2]; Syy[2]=Vyy[1]+Vyy[2]+Vyy[3]; Syy[3]=Vyy[2]+Vyy[3]+VyyR;
                Sxy[0]=VxyL+Vxy[0]+Vxy[1]; Sxy[1]=Vxy[0]+Vxy[1]+Vxy[2]; Sxy[2]=Vxy[1]+Vxy[2]+Vxy[3]; Sxy[3]=Vxy[2]+Vxy[3]+VxyR;

                const float inv9 = 1.f / 9.f;
                #pragma unroll
                for (int k = 0; k < 4; ++k) {
                    const float mux = Sx[k] * inv9;
                    const float muy = Sy[k] * inv9;
                    const float sgx = fmaxf(Sxx[k] * inv9 - mux * mux, 0.f);
                    const float sgy = fmaxf(Syy[k] * inv9 - muy * muy, 0.f);
                    const float sxy = Sxy[k] * inv9 - mux * muy;
                    const float n   = (2.f * mux * muy + P_C1) * (2.f * sxy + P_C2);
                    const float dd  = (mux * mux + muy * muy + P_C1) * (sgx + sgy + P_C2);
                    float ssim = (1.f - n * __builtin_amdgcn_rcpf(dd)) * 0.5f;  // dd >= C1*C2 > 0
                    ssim = fminf(fmaxf(ssim, 0.f), 1.f);
                    const float l1v = fabsf(xr[sc][k] - yr[sc][k]);
                    const float photo = (P_ALPHA * ssim + (1.f - P_ALPHA) * l1v) * (1.f / 3.f);
                    sum_pv += photo * vr[sc][k];
                    if (c == 0) sum_v += vr[sc][k];
                }
            }
            // (f) rotate pipeline
            if (j < RPW + 1) { pd = npd; pl = npl; pbd = npbd; pbl = npbl; }
            if (j < RPW)     { prS = nprS; phS = nphS; }
        }
    }

    // wave reduce (64 lanes) then cross-wave via tiny LDS
    #pragma unroll
    for (int off = 32; off > 0; off >>= 1) {
        sum_pv += __shfl_down(sum_pv, off, 64);
        sum_v  += __shfl_down(sum_v,  off, 64);
    }
    if (lane == 0) { redpv[wv] = sum_pv; redv[wv] = sum_v; }
    __syncthreads();
    if (tid == 0) {
        atomicAdd(&acc[0], redpv[0] + redpv[1] + redpv[2] + redpv[3]);
        atomicAdd(&acc[1], redv[0]  + redv[1]  + redv[2]  + redv[3]);
    }
}

__global__ void photo_loss_finalize(const float* __restrict__ acc,
                                    float* __restrict__ out)
{
    out[0] = acc[0] / fmaxf(acc[1], 1.f);
}

extern "C" void kernel_launch(void* const* d_in, const int* in_sizes, int n_in,
                              void* d_out, int out_size, void* d_ws, size_t ws_size,
                              hipStream_t stream)
{
    const float* disp  = (const float*)d_in[0];
    const float* left  = (const float*)d_in[1];
    const float* right = (const float*)d_in[2];
    float* out = (float*)d_out;
    float* acc = (float*)d_ws;

    hipMemsetAsync(acc, 0, 2 * sizeof(float), stream);

    // x: 5 strips of 256 px; y: 720 / (4 waves * 6 rows) = 30; z: batch
    dim3 grid(5, H_ / (NW * RPW), 8);
    dim3 block(256);
    photo_loss_kernel<<<grid, block, 0, stream>>>(disp, left, right, acc);
    photo_loss_finalize<<<1, 1, 0, stream>>>(acc, out);
}